// Round 11
// baseline (60.445 us; speedup 1.0000x reference)
//
#include <hip/hip_runtime.h>

// ReflexPolicy fused v11 = v10 + launch_bounds(256,1) (VGPR cap 256, still 8
// waves/CU) + fully-named deep LDS prefetch: all 25 A float4s then all 16 W
// float4s loaded back-to-back -> one lgkmcnt wait per phase instead of ~10.

#define TOBS 64
#define TACT 32
#define TLAT 25
#define TB   8192
#define BT   16
#define NCH  16         // chunks of 4 o's
#define HSTR 68

#define DPP_ADD(x, ctrl) \
  ((x) + __builtin_bit_cast(float, __builtin_amdgcn_update_dpp( \
      0, __builtin_bit_cast(int, (x)), (ctrl), 0xF, 0xF, true)))

__device__ __forceinline__ float halfwave_sum(float x) {
    x = DPP_ADD(x, 0xB1);   // xor1
    x = DPP_ADD(x, 0x4E);   // xor2
    x = DPP_ADD(x, 0x141);  // row_half_mirror == xor4
    x = DPP_ADD(x, 0x140);  // row_mirror      == xor8
    int y = __builtin_amdgcn_ds_swizzle(__builtin_bit_cast(int, x), 0x401F); // xor16
    return x + __builtin_bit_cast(float, y);
}

__device__ __forceinline__ float sigmoidf_(float x) {
    return 1.0f / (1.0f + __expf(-x));
}

__global__ __launch_bounds__(256, 1)
void reflex_fused(const float* __restrict__ obs,
                  const float* __restrict__ sw1, const float* __restrict__ sb1,
                  const float* __restrict__ sw2, const float* __restrict__ sb2,
                  const float* __restrict__ sw3, const float* __restrict__ sb3,
                  const float* __restrict__ rw1, const float* __restrict__ rb1,
                  const float* __restrict__ rw2, const float* __restrict__ rb2,
                  const float* __restrict__ am,  float* __restrict__ out)
{
    __shared__ __align__(16) float obs_s[BT * HSTR];
    __shared__ __align__(16) float lat_s[BT * 26];
    __shared__ __align__(16) union {
        struct { float h1[BT * HSTR]; float h2[BT * HSTR]; } p1;
        struct { float4 At4[2][25 * 32]; float4 W4[2][16 * 32]; } p2;
    } U;

    const int tid  = threadIdx.x;
    const int row0 = blockIdx.x * BT;

    // ---------------- Phase 1: supervisor (weights from L2) ----------------
    {
        const int r = tid >> 4, f = tid & 15;
        *(float4*)&obs_s[r * HSTR + f * 4] =
            *(const float4*)&obs[(row0 + r) * TOBS + f * 4];
    }
    __syncthreads();

    {   // layer 1
        const int r = tid >> 4, j0 = (tid & 15) * 4;
        float4 acc = *(const float4*)&sb1[j0];
        #pragma unroll 8
        for (int k = 0; k < 64; ++k) {
            float x = obs_s[r * HSTR + k];
            const float4 w = *(const float4*)&sw1[k * 64 + j0];
            acc.x = fmaf(x, w.x, acc.x); acc.y = fmaf(x, w.y, acc.y);
            acc.z = fmaf(x, w.z, acc.z); acc.w = fmaf(x, w.w, acc.w);
        }
        *(float4*)&U.p1.h1[r * HSTR + j0] =
            make_float4(fmaxf(acc.x, 0.f), fmaxf(acc.y, 0.f),
                        fmaxf(acc.z, 0.f), fmaxf(acc.w, 0.f));
    }
    __syncthreads();

    {   // layer 2
        const int r = tid >> 4, j0 = (tid & 15) * 4;
        float4 acc = *(const float4*)&sb2[j0];
        #pragma unroll 8
        for (int k = 0; k < 64; ++k) {
            float x = U.p1.h1[r * HSTR + k];
            const float4 w = *(const float4*)&sw2[k * 64 + j0];
            acc.x = fmaf(x, w.x, acc.x); acc.y = fmaf(x, w.y, acc.y);
            acc.z = fmaf(x, w.z, acc.z); acc.w = fmaf(x, w.w, acc.w);
        }
        *(float4*)&U.p1.h2[r * HSTR + j0] =
            make_float4(fmaxf(acc.x, 0.f), fmaxf(acc.y, 0.f),
                        fmaxf(acc.z, 0.f), fmaxf(acc.w, 0.f));
    }
    __syncthreads();

    {   // layer 3 -> lat_s
        const int r = tid >> 4, q = tid & 15;
        if (q < 13) {
            const int j = q * 2;
            float a0 = sb3[j];
            float a1 = (j + 1 < TLAT) ? sb3[j + 1] : 0.f;
            #pragma unroll 8
            for (int k = 0; k < 64; ++k) {
                float x = U.p1.h2[r * HSTR + k];
                a0 = fmaf(x, sw3[k * TLAT + j], a0);
                if (j + 1 < TLAT) a1 = fmaf(x, sw3[k * TLAT + j + 1], a1);
            }
            lat_s[r * 26 + j] = sigmoidf_(a0);
            if (j + 1 < TLAT) lat_s[r * 26 + j + 1] = sigmoidf_(a1);
        }
    }
    __syncthreads();   // lat_s ready; h1/h2 (union) dead

    // ---------------- Phase 2 ----------------
    const int a  = tid & 31;
    const int hw = tid >> 5;
    const int r0 = hw * 2, r1 = r0 + 1;

    float latA[TLAT], latB[TLAT];
    #pragma unroll
    for (int l = 0; l < TLAT; ++l) {
        latA[l] = lat_s[r0 * 26 + l];
        latB[l] = lat_s[r1 * 26 + l];
    }

    // W word k source for reflex net n (= (c*4+o)*32 + a):
    auto wload = [&](int k, int n) -> float {
        if (k < 5)  return rw1[n * 5 + k];
        if (k < 10) return rb1[n * 5 + (k - 5)];
        if (k < 15) return rw2[n * 5 + (k - 10)];
        return rb2[n];
    };

    // Stage chunk c into buffer b (v10 verbatim).
    auto stage = [&](int c, int b) {
        const int cb = c * 128;
        {
            int e = tid, l = e >> 5, a_ = e & 31;
            const float* g = am + l * 2048 + cb + a_;
            float4 v; v.x = g[0]; v.y = g[32]; v.z = g[64]; v.w = g[96];
            U.p2.At4[b][e] = v;

            e = tid + 256; l = e >> 5; a_ = e & 31;
            const float* g2 = am + l * 2048 + cb + a_;
            float4 v2; v2.x = g2[0]; v2.y = g2[32]; v2.z = g2[64]; v2.w = g2[96];
            U.p2.At4[b][e] = v2;

            e = tid + 512; l = e >> 5; a_ = e & 31;
            const float* g3 = am + l * 2048 + cb + a_;
            float4 v3; v3.x = g3[0]; v3.y = g3[32]; v3.z = g3[64]; v3.w = g3[96];
            U.p2.At4[b][e] = v3;

            if (tid < 32) {
                e = tid + 768;                       // l = 24
                const float* g4 = am + 24 * 2048 + cb + tid;
                float4 v4; v4.x = g4[0]; v4.y = g4[32]; v4.z = g4[64]; v4.w = g4[96];
                U.p2.At4[b][e] = v4;
            }
        }
        {
            int k = tid >> 5, a_ = tid & 31;
            int n0 = cb + a_;
            float4 w;
            w.x = wload(k, n0);      w.y = wload(k, n0 + 32);
            w.z = wload(k, n0 + 64); w.w = wload(k, n0 + 96);
            U.p2.W4[b][tid] = w;

            k += 8;
            float4 w2;
            w2.x = wload(k, n0);      w2.y = wload(k, n0 + 32);
            w2.z = wload(k, n0 + 64); w2.w = wload(k, n0 + 96);
            U.p2.W4[b][tid + 256] = w2;
        }
    };

    float acc0 = 0.f, acc1 = 0.f;

    stage(0, 0);
    __syncthreads();

    for (int c = 0; c < NCH; ++c) {
        const float4* A4 = U.p2.At4[c & 1];
        const float4* Wb = U.p2.W4[c & 1];

        // ---- deep prefetch: ALL 25 A float4s as named regs, back-to-back
        #define LOADA(i) const float4 A_##i = A4[(i) * 32 + a];
        LOADA(0)  LOADA(1)  LOADA(2)  LOADA(3)  LOADA(4)
        LOADA(5)  LOADA(6)  LOADA(7)  LOADA(8)  LOADA(9)
        LOADA(10) LOADA(11) LOADA(12) LOADA(13) LOADA(14)
        LOADA(15) LOADA(16) LOADA(17) LOADA(18) LOADA(19)
        LOADA(20) LOADA(21) LOADA(22) LOADA(23) LOADA(24)
        #undef LOADA

        float l00 = 0.f, l01 = 0.f, l02 = 0.f, l03 = 0.f;
        float l10 = 0.f, l11 = 0.f, l12 = 0.f, l13 = 0.f;
        #define DOT8(i) \
            l00 = fmaf(A_##i.x, latA[i], l00); l10 = fmaf(A_##i.x, latB[i], l10); \
            l01 = fmaf(A_##i.y, latA[i], l01); l11 = fmaf(A_##i.y, latB[i], l11); \
            l02 = fmaf(A_##i.z, latA[i], l02); l12 = fmaf(A_##i.z, latB[i], l12); \
            l03 = fmaf(A_##i.w, latA[i], l03); l13 = fmaf(A_##i.w, latB[i], l13);
        DOT8(0)  DOT8(1)  DOT8(2)  DOT8(3)  DOT8(4)
        DOT8(5)  DOT8(6)  DOT8(7)  DOT8(8)  DOT8(9)
        DOT8(10) DOT8(11) DOT8(12) DOT8(13) DOT8(14)
        DOT8(15) DOT8(16) DOT8(17) DOT8(18) DOT8(19)
        DOT8(20) DOT8(21) DOT8(22) DOT8(23) DOT8(24)
        #undef DOT8

        // ---- prefetch all 16 W float4s (A regs dead -> reuse)
        #define LOADW(i) const float4 W_##i = Wb[(i) * 32 + a];
        LOADW(0)  LOADW(1)  LOADW(2)  LOADW(3)
        LOADW(4)  LOADW(5)  LOADW(6)  LOADW(7)
        LOADW(8)  LOADW(9)  LOADW(10) LOADW(11)
        LOADW(12) LOADW(13) LOADW(14) LOADW(15)
        #undef LOADW

        // ---- softmax over a (32-lane half-wave), 8 independent chains
        float e00 = __expf(l00), e01 = __expf(l01), e02 = __expf(l02), e03 = __expf(l03);
        float e10 = __expf(l10), e11 = __expf(l11), e12 = __expf(l12), e13 = __expf(l13);
        float p00 = e00 * __builtin_amdgcn_rcpf(halfwave_sum(e00));
        float p01 = e01 * __builtin_amdgcn_rcpf(halfwave_sum(e01));
        float p02 = e02 * __builtin_amdgcn_rcpf(halfwave_sum(e02));
        float p03 = e03 * __builtin_amdgcn_rcpf(halfwave_sum(e03));
        float p10 = e10 * __builtin_amdgcn_rcpf(halfwave_sum(e10));
        float p11 = e11 * __builtin_amdgcn_rcpf(halfwave_sum(e11));
        float p12 = e12 * __builtin_amdgcn_rcpf(halfwave_sum(e12));
        float p13 = e13 * __builtin_amdgcn_rcpf(halfwave_sum(e13));

        // ---- reflex MLPs: W_h = w1[h], W_{5+h} = b1[h], W_{10+h} = w2[h], W_15 = b2
        const int ob = c * 4;
        const float x00 = obs_s[r0 * HSTR + ob],     x10 = obs_s[r1 * HSTR + ob];
        const float x01 = obs_s[r0 * HSTR + ob + 1], x11 = obs_s[r1 * HSTR + ob + 1];
        const float x02 = obs_s[r0 * HSTR + ob + 2], x12 = obs_s[r1 * HSTR + ob + 2];
        const float x03 = obs_s[r0 * HSTR + ob + 3], x13 = obs_s[r1 * HSTR + ob + 3];

        float q00 = W_15.x, q01 = W_15.y, q02 = W_15.z, q03 = W_15.w;
        float q10 = W_15.x, q11 = W_15.y, q12 = W_15.z, q13 = W_15.w;
        #define RFLX(h, W1V, B1V, W2V) \
            q00 = fmaf(fmaxf(fmaf(x00, W1V.x, B1V.x), 0.f), W2V.x, q00); \
            q10 = fmaf(fmaxf(fmaf(x10, W1V.x, B1V.x), 0.f), W2V.x, q10); \
            q01 = fmaf(fmaxf(fmaf(x01, W1V.y, B1V.y), 0.f), W2V.y, q01); \
            q11 = fmaf(fmaxf(fmaf(x11, W1V.y, B1V.y), 0.f), W2V.y, q11); \
            q02 = fmaf(fmaxf(fmaf(x02, W1V.z, B1V.z), 0.f), W2V.z, q02); \
            q12 = fmaf(fmaxf(fmaf(x12, W1V.z, B1V.z), 0.f), W2V.z, q12); \
            q03 = fmaf(fmaxf(fmaf(x03, W1V.w, B1V.w), 0.f), W2V.w, q03); \
            q13 = fmaf(fmaxf(fmaf(x13, W1V.w, B1V.w), 0.f), W2V.w, q13);
        RFLX(0, W_0, W_5, W_10)
        RFLX(1, W_1, W_6, W_11)
        RFLX(2, W_2, W_7, W_12)
        RFLX(3, W_3, W_8, W_13)
        RFLX(4, W_4, W_9, W_14)
        #undef RFLX

        acc0 = fmaf(q00, p00, acc0); acc1 = fmaf(q10, p10, acc1);
        acc0 = fmaf(q01, p01, acc0); acc1 = fmaf(q11, p11, acc1);
        acc0 = fmaf(q02, p02, acc0); acc1 = fmaf(q12, p12, acc1);
        acc0 = fmaf(q03, p03, acc0); acc1 = fmaf(q13, p13, acc1);

        if (c + 1 < NCH) stage(c + 1, (c + 1) & 1);  // v5/v10 protocol: stage after compute
        __syncthreads();
    }

    out[(row0 + r0) * TACT + a] = acc0;
    out[(row0 + r1) * TACT + a] = acc1;
}

extern "C" void kernel_launch(void* const* d_in, const int* in_sizes, int n_in,
                              void* d_out, int out_size, void* d_ws, size_t ws_size,
                              hipStream_t stream) {
    const float* obs = (const float*)d_in[0];
    const float* sw1 = (const float*)d_in[1];
    const float* sb1 = (const float*)d_in[2];
    const float* sw2 = (const float*)d_in[3];
    const float* sb2 = (const float*)d_in[4];
    const float* sw3 = (const float*)d_in[5];
    const float* sb3 = (const float*)d_in[6];
    const float* rw1 = (const float*)d_in[7];
    const float* rb1 = (const float*)d_in[8];
    const float* rw2 = (const float*)d_in[9];
    const float* rb2 = (const float*)d_in[10];
    const float* am  = (const float*)d_in[11];
    float* out = (float*)d_out;

    reflex_fused<<<TB / BT, 256, 0, stream>>>(obs, sw1, sb1, sw2, sb2, sw3, sb3,
                                              rw1, rb1, rw2, rb2, am, out);
}